// Round 7
// baseline (2371.508 us; speedup 1.0000x reference)
//
#include <hip/hip_runtime.h>
#include <stdint.h>

#define Bv 64
#define Tv 512
#define Dv 256
#define Uv 512
#define WPG 32   // workgroups per row-group; each owns 16 u-cols x 3 gates

typedef __attribute__((ext_vector_type(8))) __bf16 bf16x8;
typedef __attribute__((ext_vector_type(8))) short short8;
typedef __attribute__((ext_vector_type(4))) float f32x4;
typedef unsigned long long u64;

// Persistent device globals (zero at module load; never poisoned by harness).
// g_flag[g][c][w]: epoch flag = (gen-1)*512 + (t+1) after WAVE w of producer
//   c (group g) finished its quarter (rows w*4..w*4+3) of step t. Per-wave
//   publish removes the producer-side barrier+full-WG drain from the chain.
//   Monotonic across launches -> graph-replay safe.
// g_hbuf: double-buffered h exchange, U-PAIRED TRANSPOSED layout
//   [slot][u>>1][b][u&1] (dwords): one u64 = two adjacent u for one b.
//   Consumer gathers 16 u64 loads/lane; producer writes independent dword
//   halves (tear-free; the pair belongs to one producer WG).
__device__ unsigned int g_flag[4 * WPG * 4];
__device__ unsigned int g_gen[4 * WPG];
__device__ u64 g_hbuf[2 * Bv * Uv / 2];

__device__ __forceinline__ unsigned int f2bf_bits(float x) {
    unsigned int u = __float_as_uint(x);
    return (u + 0x7fffu + ((u >> 16) & 1u)) >> 16;   // RNE to bf16
}
__device__ __forceinline__ float bfbits2f(unsigned int b) {
    return __uint_as_float(b << 16);
}
__device__ __forceinline__ float fast_sigmoid(float x) {
    return __builtin_amdgcn_rcpf(1.f + __expf(-x));
}
__device__ __forceinline__ float fast_tanh(float x) {
    float ax = fabsf(x);
    float t  = __expf(-2.f * ax);
    float r  = (1.f - t) * __builtin_amdgcn_rcpf(1.f + t);
    return x < 0.f ? -r : r;
}

extern "C" __global__ void __launch_bounds__(256, 1)
noglstm_kernel(const float* __restrict__ x,
               const float* __restrict__ w_xi, const float* __restrict__ w_xf, const float* __restrict__ w_xc,
               const float* __restrict__ w_hi, const float* __restrict__ w_hf, const float* __restrict__ w_hc,
               const float* __restrict__ b_i, const float* __restrict__ b_f, const float* __restrict__ b_c,
               const float* __restrict__ h0, const float* __restrict__ c0,
               float* __restrict__ out)
{
    __shared__ f32x4 partLds[2][12 * 64];          // 24 KB: double-buffered reduce
    __shared__ float cTile[256];                   // persistent c state [16r x 16u]
    __shared__ float biasLds[48];
    __shared__ unsigned int baseLds;

    const int tid  = threadIdx.x;
    const int wg   = blockIdx.x;
    const int g    = wg >> 5;          // row group 0..3 (16 batch rows)
    const int c    = wg & 31;          // producer index within group
    const int r0   = g * 16;
    const int u0   = c * 16;
    const int wv   = tid >> 6;         // wave 0..3 = k-quarter
    const int lane = tid & 63;
    const int n    = lane & 15;
    const int quad = lane >> 4;
    const int kh   = wv;
    const int m    = n;                // fragment row
    const int q    = quad;             // fragment k-subblock

    if (tid == 0) { unsigned v = g_gen[wg] + 1u; g_gen[wg] = v; baseLds = (v - 1u) * (unsigned)Tv; }
    if (tid < 16)      biasLds[tid]      = b_i[u0 + tid];
    else if (tid < 32) biasLds[tid]      = b_f[u0 + tid - 16];
    else if (tid < 48) biasLds[tid]      = b_c[u0 + tid - 32];
    cTile[tid] = c0[(size_t)(r0 + (tid >> 4)) * Uv + u0 + (tid & 15)];

    // ---- W fragments: registers, bf16 hi/lo split, gathered once ----
    const float* WhP[3] = {w_hi, w_hf, w_hc};
    const float* WxP[3] = {w_xi, w_xf, w_xc};
    const int ucol = u0 + n;

    bf16x8 whHiR[3][4], whLoR[3][4], wxHiR[3][2], wxLoR[3][2];
    #pragma unroll
    for (int nt = 0; nt < 3; ++nt) {
        #pragma unroll
        for (int i = 0; i < 4; ++i) {
            short8 hi8, lo8;
            #pragma unroll
            for (int e = 0; e < 8; ++e) {
                int k = (kh * 4 + i) * 32 + quad * 8 + e;
                float w = WhP[nt][(size_t)k * Uv + ucol];
                unsigned int hb = f2bf_bits(w);
                unsigned int lb = f2bf_bits(w - bfbits2f(hb));
                hi8[e] = (short)hb; lo8[e] = (short)lb;
            }
            whHiR[nt][i] = __builtin_bit_cast(bf16x8, hi8);
            whLoR[nt][i] = __builtin_bit_cast(bf16x8, lo8);
        }
        #pragma unroll
        for (int i = 0; i < 2; ++i) {
            short8 hi8, lo8;
            #pragma unroll
            for (int e = 0; e < 8; ++e) {
                int k = (kh * 2 + i) * 32 + quad * 8 + e;
                float w = WxP[nt][(size_t)k * Uv + ucol];
                unsigned int hb = f2bf_bits(w);
                unsigned int lb = f2bf_bits(w - bfbits2f(hb));
                hi8[e] = (short)hb; lo8[e] = (short)lb;
            }
            wxHiR[nt][i] = __builtin_bit_cast(bf16x8, hi8);
            wxLoR[nt][i] = __builtin_bit_cast(bf16x8, lo8);
        }
    }

    // ---- prime: issue x(0) loads (converted at step head) ----
    f32x4 xf[4];
    #pragma unroll
    for (int i = 0; i < 2; ++i) {
        int kt = kh * 2 + i;
        const float* p = x + ((size_t)(r0 + m) * Tv + 0) * Dv + kt * 32 + q * 8;
        xf[i * 2]     = *(const f32x4*)p;
        xf[i * 2 + 1] = *(const f32x4*)(p + 4);
    }
    __syncthreads();   // baseLds / biasLds / cTile visible
    const unsigned int base = baseLds;

    // wave wv consumes h cols [kh*128, +128) -> producers kh*8 .. kh*8+7,
    // each with 4 wave-flags: 32 contiguous dwords at [g][kh*8][0].
    const unsigned int* fpw = g_flag + (g * WPG + kh * 8) * 4;

    for (int t = 0; t < Tv; ++t) {
        const bool packed = (t != 0);
        const bool pfch = (t + 1 < Tv);
        const int par = t & 1;
        u64 hw64[16];
        f32x4 hf[8];

        // ---- 1. per-wave flag poll: 32 dwords on 2 cache lines ----
        if (packed) {
            const unsigned int E = base + (unsigned)t;
            unsigned int fv = 0xFFFFFFFFu;
            unsigned int spins = 0;
            for (;;) {
                if (lane < 32)
                    fv = __hip_atomic_load(fpw + lane, __ATOMIC_RELAXED,
                                           __HIP_MEMORY_SCOPE_AGENT);
                if (__all((lane >= 32) || (fv >= E))) break;
                if (++spins > (1u << 20)) break;       // bounded: fail loud
                if (spins > 16) __builtin_amdgcn_s_sleep(1);
            }
            __asm__ volatile("" ::: "memory");         // no hoisting loads above poll

            // ---- 2. h(t-1) gather: 16 u64 loads, paired-transposed layout ----
            const u64* hb = g_hbuf + (size_t)((t - 1) & 1) * (Bv * Uv / 2);
            #pragma unroll
            for (int i = 0; i < 4; ++i) {
                int kt = kh * 4 + i;
                const u64* p = hb + (size_t)(kt * 16 + q * 4) * Bv + r0 + m;
                #pragma unroll
                for (int j = 0; j < 4; ++j)
                    hw64[i * 4 + j] = __hip_atomic_load(p + (size_t)j * Bv,
                                                        __ATOMIC_RELAXED,
                                                        __HIP_MEMORY_SCOPE_AGENT);
            }
        } else {
            #pragma unroll
            for (int i = 0; i < 4; ++i) {
                int kt = kh * 4 + i;
                const float* p = h0 + (size_t)(r0 + m) * Uv + kt * 32 + q * 8;
                hf[i * 2]     = *(const f32x4*)p;
                hf[i * 2 + 1] = *(const f32x4*)(p + 4);
            }
        }

        // ---- 3. convert x(t) regs (loads issued in last tail) ----
        bf16x8 xaH[2], xaL[2];
        #pragma unroll
        for (int i = 0; i < 2; ++i) {
            short8 hi8, lo8;
            #pragma unroll
            for (int e = 0; e < 8; ++e) {
                float v = (e < 4) ? xf[i * 2][e] : xf[i * 2 + 1][e - 4];
                unsigned int hb2 = f2bf_bits(v);
                unsigned int lb2 = f2bf_bits(v - bfbits2f(hb2));
                hi8[e] = (short)hb2; lo8[e] = (short)lb2;
            }
            xaH[i] = __builtin_bit_cast(bf16x8, hi8);
            xaL[i] = __builtin_bit_cast(bf16x8, lo8);
        }

        // ---- 4. x-part MFMA overlaps the h gather latency ----
        f32x4 acc[3], accX[3];
        #pragma unroll
        for (int nt = 0; nt < 3; ++nt) { acc[nt] = f32x4{0.f,0.f,0.f,0.f}; accX[nt] = f32x4{0.f,0.f,0.f,0.f}; }
        #pragma unroll
        for (int i = 0; i < 2; ++i) {
            #pragma unroll
            for (int nt = 0; nt < 3; ++nt) {
                accX[nt] = __builtin_amdgcn_mfma_f32_16x16x32_bf16(xaH[i], wxHiR[nt][i], accX[nt], 0, 0, 0);
                accX[nt] = __builtin_amdgcn_mfma_f32_16x16x32_bf16(xaH[i], wxLoR[nt][i], accX[nt], 0, 0, 0);
                accX[nt] = __builtin_amdgcn_mfma_f32_16x16x32_bf16(xaL[i], wxHiR[nt][i], accX[nt], 0, 0, 0);
                accX[nt] = __builtin_amdgcn_mfma_f32_16x16x32_bf16(xaL[i], wxLoR[nt][i], accX[nt], 0, 0, 0);
            }
        }

        // ---- 5. per-chunk unpack + h-MFMA (direct from regs) ----
        #pragma unroll
        for (int i = 0; i < 4; ++i) {
            bf16x8 haH, haL;
            if (packed) {
                short8 hi8, lo8;
                #pragma unroll
                for (int j = 0; j < 4; ++j) {
                    u64 w = hw64[i * 4 + j];
                    unsigned int d0 = (unsigned int)w;
                    unsigned int d1 = (unsigned int)(w >> 32);
                    hi8[2 * j]     = (short)(d0 >> 16);
                    lo8[2 * j]     = (short)(d0 & 0xffffu);
                    hi8[2 * j + 1] = (short)(d1 >> 16);
                    lo8[2 * j + 1] = (short)(d1 & 0xffffu);
                }
                haH = __builtin_bit_cast(bf16x8, hi8);
                haL = __builtin_bit_cast(bf16x8, lo8);
            } else {
                short8 hi8, lo8;
                #pragma unroll
                for (int e = 0; e < 8; ++e) {
                    float v = (e < 4) ? hf[i * 2][e] : hf[i * 2 + 1][e - 4];
                    unsigned int hb2 = f2bf_bits(v);
                    unsigned int lb2 = f2bf_bits(v - bfbits2f(hb2));
                    hi8[e] = (short)hb2; lo8[e] = (short)lb2;
                }
                haH = __builtin_bit_cast(bf16x8, hi8);
                haL = __builtin_bit_cast(bf16x8, lo8);
            }
            #pragma unroll
            for (int nt = 0; nt < 3; ++nt) {
                acc[nt] = __builtin_amdgcn_mfma_f32_16x16x32_bf16(haH, whHiR[nt][i], acc[nt], 0, 0, 0);
                acc[nt] = __builtin_amdgcn_mfma_f32_16x16x32_bf16(haH, whLoR[nt][i], acc[nt], 0, 0, 0);
                acc[nt] = __builtin_amdgcn_mfma_f32_16x16x32_bf16(haL, whHiR[nt][i], acc[nt], 0, 0, 0);
                acc[nt] = __builtin_amdgcn_mfma_f32_16x16x32_bf16(haL, whLoR[nt][i], acc[nt], 0, 0, 0);
            }
        }

        #pragma unroll
        for (int nt = 0; nt < 3; ++nt) {
            acc[nt][0] += accX[nt][0]; acc[nt][1] += accX[nt][1];
            acc[nt][2] += accX[nt][2]; acc[nt][3] += accX[nt][3];
            partLds[par][(wv * 3 + nt) * 64 + lane] = acc[nt];
        }
        __syncthreads();   // (A) the ONLY barrier per step: cross-wave reduce

        // ---- 6. epilogue: one output element per thread (wave wv owns rows
        // wv*4..wv*4+3), then PER-WAVE drain + wave-flag publish: no barrier B.
        const int r = tid >> 4, uu = tid & 15;
        float hn;
        {
            int plane = (r >> 2) * 16 + uu;       // D layout: col=lane&15, row=quad*4+reg
            int reg = r & 3;
            const float* pf2 = (const float*)partLds[par];
            float pi = biasLds[uu], pF = biasLds[16 + uu], pc = biasLds[32 + uu];
            #pragma unroll
            for (int w = 0; w < 4; ++w) {
                pi += pf2[((w * 3 + 0) * 64 + plane) * 4 + reg];
                pF += pf2[((w * 3 + 1) * 64 + plane) * 4 + reg];
                pc += pf2[((w * 3 + 2) * 64 + plane) * 4 + reg];
            }
            float iv  = fast_sigmoid(pi);
            float fv  = fast_sigmoid(pF);
            float cin = fast_tanh(pc);
            float cn  = fv * cTile[tid] + iv * cin;
            cTile[tid] = cn;
            hn = fast_tanh(cn);
            unsigned int hbb = f2bf_bits(hn);
            unsigned int lbb = f2bf_bits(hn - bfbits2f(hbb));
            unsigned int* hb32 = (unsigned int*)g_hbuf;
            size_t di = (size_t)par * (Bv * Uv)
                      + ((size_t)((u0 + uu) >> 1) * Bv + (r0 + r)) * 2 + (uu & 1);
            __hip_atomic_store(hb32 + di, (hbb << 16) | lbb, __ATOMIC_RELAXED,
                               __HIP_MEMORY_SCOPE_AGENT);
        }

        // ---- 7. wave-local drain (this wave's 64 h stores), publish wave-flag.
        // Wave-level s_waitcnt: flag raised only after the wave's data is at
        // the coherence point. Consumers poll all 4 wave-flags per producer.
        __asm__ volatile("s_waitcnt vmcnt(0)" ::: "memory");
        if (lane == 0)
            __hip_atomic_store(&g_flag[(g * WPG + c) * 4 + wv],
                               base + (unsigned)t + 1u,
                               __ATOMIC_RELAXED, __HIP_MEMORY_SCOPE_AGENT);

        // ---- 8. tail (off inter-WG critical path): out store, x(t+1) issue ----
        out[((size_t)(r0 + r) * Tv + t) * Uv + u0 + uu] = hn;

        if (pfch) {
            #pragma unroll
            for (int i = 0; i < 2; ++i) {
                int kt = kh * 2 + i;
                const float* p = x + ((size_t)(r0 + m) * Tv + (t + 1)) * Dv + kt * 32 + q * 8;
                xf[i * 2]     = *(const f32x4*)p;
                xf[i * 2 + 1] = *(const f32x4*)(p + 4);
            }
        }
        // no tail barrier: next step writes partLds[par^1]; this step's
        // epilogue read partLds[par] -> no hazard (double buffer).
    }
}

extern "C" void kernel_launch(void* const* d_in, const int* in_sizes, int n_in,
                              void* d_out, int out_size, void* d_ws, size_t ws_size,
                              hipStream_t stream) {
    (void)in_sizes; (void)n_in; (void)out_size; (void)d_ws; (void)ws_size;
    noglstm_kernel<<<dim3(128), dim3(256), 0, stream>>>(
        (const float*)d_in[0],
        (const float*)d_in[1], (const float*)d_in[2], (const float*)d_in[3],
        (const float*)d_in[4], (const float*)d_in[5], (const float*)d_in[6],
        (const float*)d_in[7], (const float*)d_in[8], (const float*)d_in[9],
        (const float*)d_in[10], (const float*)d_in[11],
        (float*)d_out);
}

// Round 8
// 1869.826 us; speedup vs baseline: 1.2683x; 1.2683x over previous
//
#include <hip/hip_runtime.h>
#include <stdint.h>

#define Bv 64
#define Tv 512
#define Dv 256
#define Uv 512
#define WPG 32     // workgroups per row-group; each owns 16 u-cols x 3 gates
#define FPAD 16    // flag padding: one flag per 64B line (kills false sharing)

typedef __attribute__((ext_vector_type(8))) __bf16 bf16x8;
typedef __attribute__((ext_vector_type(8))) short short8;
typedef __attribute__((ext_vector_type(4))) float f32x4;
typedef unsigned long long u64;

// Persistent device globals (zero at module load; never poisoned by harness).
// g_flag[(g*32+c)*FPAD]: epoch flag = (gen-1)*512 + (t+1) after producer c of
//   group g finished step t. ONE FLAG PER 64B LINE: producers store to private
//   lines; pollers read 8 distinct lines -> no read/write line contention.
//   Monotonic across launches -> graph-replay safe.
// g_hbuf: double-buffered h exchange, U-PAIRED TRANSPOSED layout
//   [slot][u>>1][b][u&1] (dwords): one u64 = two adjacent u for one b.
//   Consumer gathers 16 u64 loads/lane; producer writes independent dword
//   halves (tear-free; the pair belongs to one producer WG).
__device__ unsigned int g_flag[4 * WPG * FPAD];
__device__ unsigned int g_gen[4 * WPG];
__device__ u64 g_hbuf[2 * Bv * Uv / 2];

__device__ __forceinline__ unsigned int f2bf_bits(float x) {
    unsigned int u = __float_as_uint(x);
    return (u + 0x7fffu + ((u >> 16) & 1u)) >> 16;   // RNE to bf16
}
__device__ __forceinline__ float bfbits2f(unsigned int b) {
    return __uint_as_float(b << 16);
}
__device__ __forceinline__ float fast_sigmoid(float x) {
    return __builtin_amdgcn_rcpf(1.f + __expf(-x));
}
__device__ __forceinline__ float fast_tanh(float x) {
    float ax = fabsf(x);
    float t  = __expf(-2.f * ax);
    float r  = (1.f - t) * __builtin_amdgcn_rcpf(1.f + t);
    return x < 0.f ? -r : r;
}

extern "C" __global__ void __launch_bounds__(256, 1)
noglstm_kernel(const float* __restrict__ x,
               const float* __restrict__ w_xi, const float* __restrict__ w_xf, const float* __restrict__ w_xc,
               const float* __restrict__ w_hi, const float* __restrict__ w_hf, const float* __restrict__ w_hc,
               const float* __restrict__ b_i, const float* __restrict__ b_f, const float* __restrict__ b_c,
               const float* __restrict__ h0, const float* __restrict__ c0,
               float* __restrict__ out)
{
    __shared__ f32x4 partLds[12 * 64];             // 12 KB: 4 waves x 3 gates
    __shared__ float cTile[256];                   // persistent c state [16r x 16u]
    __shared__ float biasLds[48];
    __shared__ unsigned int baseLds;

    const int tid  = threadIdx.x;
    const int wg   = blockIdx.x;
    const int g    = wg >> 5;          // row group 0..3 (16 batch rows)
    const int c    = wg & 31;          // producer index within group
    const int r0   = g * 16;
    const int u0   = c * 16;
    const int wv   = tid >> 6;         // wave 0..3 = k-quarter
    const int lane = tid & 63;
    const int n    = lane & 15;
    const int quad = lane >> 4;
    const int kh   = wv;
    const int m    = n;                // fragment row
    const int q    = quad;             // fragment k-subblock

    if (tid == 0) { unsigned v = g_gen[wg] + 1u; g_gen[wg] = v; baseLds = (v - 1u) * (unsigned)Tv; }
    if (tid < 16)      biasLds[tid]      = b_i[u0 + tid];
    else if (tid < 32) biasLds[tid]      = b_f[u0 + tid - 16];
    else if (tid < 48) biasLds[tid]      = b_c[u0 + tid - 32];
    cTile[tid] = c0[(size_t)(r0 + (tid >> 4)) * Uv + u0 + (tid & 15)];

    // ---- W fragments: registers, bf16 hi/lo split, gathered once ----
    const float* WhP[3] = {w_hi, w_hf, w_hc};
    const float* WxP[3] = {w_xi, w_xf, w_xc};
    const int ucol = u0 + n;

    bf16x8 whHiR[3][4], whLoR[3][4], wxHiR[3][2], wxLoR[3][2];
    #pragma unroll
    for (int nt = 0; nt < 3; ++nt) {
        #pragma unroll
        for (int i = 0; i < 4; ++i) {
            short8 hi8, lo8;
            #pragma unroll
            for (int e = 0; e < 8; ++e) {
                int k = (kh * 4 + i) * 32 + quad * 8 + e;
                float w = WhP[nt][(size_t)k * Uv + ucol];
                unsigned int hb = f2bf_bits(w);
                unsigned int lb = f2bf_bits(w - bfbits2f(hb));
                hi8[e] = (short)hb; lo8[e] = (short)lb;
            }
            whHiR[nt][i] = __builtin_bit_cast(bf16x8, hi8);
            whLoR[nt][i] = __builtin_bit_cast(bf16x8, lo8);
        }
        #pragma unroll
        for (int i = 0; i < 2; ++i) {
            short8 hi8, lo8;
            #pragma unroll
            for (int e = 0; e < 8; ++e) {
                int k = (kh * 2 + i) * 32 + quad * 8 + e;
                float w = WxP[nt][(size_t)k * Uv + ucol];
                unsigned int hb = f2bf_bits(w);
                unsigned int lb = f2bf_bits(w - bfbits2f(hb));
                hi8[e] = (short)hb; lo8[e] = (short)lb;
            }
            wxHiR[nt][i] = __builtin_bit_cast(bf16x8, hi8);
            wxLoR[nt][i] = __builtin_bit_cast(bf16x8, lo8);
        }
    }

    // ---- prime: issue x(0) loads (converted at step head) ----
    f32x4 xf[4];
    #pragma unroll
    for (int i = 0; i < 2; ++i) {
        int kt = kh * 2 + i;
        const float* p = x + ((size_t)(r0 + m) * Tv + 0) * Dv + kt * 32 + q * 8;
        xf[i * 2]     = *(const f32x4*)p;
        xf[i * 2 + 1] = *(const f32x4*)(p + 4);
    }
    __syncthreads();   // baseLds / biasLds / cTile visible
    const unsigned int base = baseLds;

    // wave wv consumes h cols [kh*128, +128) -> producers kh*8 .. kh*8+7;
    // padded flags: lane i<8 polls line (g*WPG + kh*8 + i)*FPAD.
    const unsigned int* fpw = g_flag + (size_t)(g * WPG + kh * 8) * FPAD;

    for (int t = 0; t < Tv; ++t) {
        const bool packed = (t != 0);
        const bool pfch = (t + 1 < Tv);
        u64 hw64[16];
        f32x4 hf[8];

        // ---- 1. per-wave flag poll: 8 private lines, one 8-lane load ----
        if (packed) {
            const unsigned int E = base + (unsigned)t;
            unsigned int fv = 0xFFFFFFFFu;
            unsigned int spins = 0;
            for (;;) {
                if (lane < 8)
                    fv = __hip_atomic_load(fpw + (size_t)lane * FPAD,
                                           __ATOMIC_RELAXED, __HIP_MEMORY_SCOPE_AGENT);
                if (__all((lane >= 8) || (fv >= E))) break;
                if (++spins > (1u << 20)) break;       // bounded: fail loud
                if (spins > 16) __builtin_amdgcn_s_sleep(1);
            }
            __asm__ volatile("" ::: "memory");         // no hoisting loads above poll

            // ---- 2. h(t-1) gather: 16 u64 loads, paired-transposed layout ----
            const u64* hb = g_hbuf + (size_t)((t - 1) & 1) * (Bv * Uv / 2);
            #pragma unroll
            for (int i = 0; i < 4; ++i) {
                int kt = kh * 4 + i;
                const u64* p = hb + (size_t)(kt * 16 + q * 4) * Bv + r0 + m;
                #pragma unroll
                for (int j = 0; j < 4; ++j)
                    hw64[i * 4 + j] = __hip_atomic_load(p + (size_t)j * Bv,
                                                        __ATOMIC_RELAXED,
                                                        __HIP_MEMORY_SCOPE_AGENT);
            }
        } else {
            #pragma unroll
            for (int i = 0; i < 4; ++i) {
                int kt = kh * 4 + i;
                const float* p = h0 + (size_t)(r0 + m) * Uv + kt * 32 + q * 8;
                hf[i * 2]     = *(const f32x4*)p;
                hf[i * 2 + 1] = *(const f32x4*)(p + 4);
            }
        }

        // ---- 3. convert x(t) regs (loads issued in last tail) ----
        bf16x8 xaH[2], xaL[2];
        #pragma unroll
        for (int i = 0; i < 2; ++i) {
            short8 hi8, lo8;
            #pragma unroll
            for (int e = 0; e < 8; ++e) {
                float v = (e < 4) ? xf[i * 2][e] : xf[i * 2 + 1][e - 4];
                unsigned int hb2 = f2bf_bits(v);
                unsigned int lb2 = f2bf_bits(v - bfbits2f(hb2));
                hi8[e] = (short)hb2; lo8[e] = (short)lb2;
            }
            xaH[i] = __builtin_bit_cast(bf16x8, hi8);
            xaL[i] = __builtin_bit_cast(bf16x8, lo8);
        }

        // ---- 4. x-part MFMA overlaps the h gather latency ----
        f32x4 acc[3], accX[3];
        #pragma unroll
        for (int nt = 0; nt < 3; ++nt) { acc[nt] = f32x4{0.f,0.f,0.f,0.f}; accX[nt] = f32x4{0.f,0.f,0.f,0.f}; }
        #pragma unroll
        for (int i = 0; i < 2; ++i) {
            #pragma unroll
            for (int nt = 0; nt < 3; ++nt) {
                accX[nt] = __builtin_amdgcn_mfma_f32_16x16x32_bf16(xaH[i], wxHiR[nt][i], accX[nt], 0, 0, 0);
                accX[nt] = __builtin_amdgcn_mfma_f32_16x16x32_bf16(xaH[i], wxLoR[nt][i], accX[nt], 0, 0, 0);
                accX[nt] = __builtin_amdgcn_mfma_f32_16x16x32_bf16(xaL[i], wxHiR[nt][i], accX[nt], 0, 0, 0);
                accX[nt] = __builtin_amdgcn_mfma_f32_16x16x32_bf16(xaL[i], wxLoR[nt][i], accX[nt], 0, 0, 0);
            }
        }

        // ---- 5. per-chunk unpack + h-MFMA (direct from regs) ----
        #pragma unroll
        for (int i = 0; i < 4; ++i) {
            bf16x8 haH, haL;
            if (packed) {
                short8 hi8, lo8;
                #pragma unroll
                for (int j = 0; j < 4; ++j) {
                    u64 w = hw64[i * 4 + j];
                    unsigned int d0 = (unsigned int)w;
                    unsigned int d1 = (unsigned int)(w >> 32);
                    hi8[2 * j]     = (short)(d0 >> 16);
                    lo8[2 * j]     = (short)(d0 & 0xffffu);
                    hi8[2 * j + 1] = (short)(d1 >> 16);
                    lo8[2 * j + 1] = (short)(d1 & 0xffffu);
                }
                haH = __builtin_bit_cast(bf16x8, hi8);
                haL = __builtin_bit_cast(bf16x8, lo8);
            } else {
                short8 hi8, lo8;
                #pragma unroll
                for (int e = 0; e < 8; ++e) {
                    float v = (e < 4) ? hf[i * 2][e] : hf[i * 2 + 1][e - 4];
                    unsigned int hb2 = f2bf_bits(v);
                    unsigned int lb2 = f2bf_bits(v - bfbits2f(hb2));
                    hi8[e] = (short)hb2; lo8[e] = (short)lb2;
                }
                haH = __builtin_bit_cast(bf16x8, hi8);
                haL = __builtin_bit_cast(bf16x8, lo8);
            }
            #pragma unroll
            for (int nt = 0; nt < 3; ++nt) {
                acc[nt] = __builtin_amdgcn_mfma_f32_16x16x32_bf16(haH, whHiR[nt][i], acc[nt], 0, 0, 0);
                acc[nt] = __builtin_amdgcn_mfma_f32_16x16x32_bf16(haH, whLoR[nt][i], acc[nt], 0, 0, 0);
                acc[nt] = __builtin_amdgcn_mfma_f32_16x16x32_bf16(haL, whHiR[nt][i], acc[nt], 0, 0, 0);
                acc[nt] = __builtin_amdgcn_mfma_f32_16x16x32_bf16(haL, whLoR[nt][i], acc[nt], 0, 0, 0);
            }
        }

        #pragma unroll
        for (int nt = 0; nt < 3; ++nt) {
            acc[nt][0] += accX[nt][0]; acc[nt][1] += accX[nt][1];
            acc[nt][2] += accX[nt][2]; acc[nt][3] += accX[nt][3];
            partLds[(wv * 3 + nt) * 64 + lane] = acc[nt];
        }
        __syncthreads();   // (A) cross-wave reduce

        // ---- 6. epilogue: one output element per thread ----
        const int r = tid >> 4, uu = tid & 15;
        float hn;
        {
            int plane = (r >> 2) * 16 + uu;       // D layout: col=lane&15, row=quad*4+reg
            int reg = r & 3;
            const float* pf2 = (const float*)partLds;
            float pi = biasLds[uu], pF = biasLds[16 + uu], pc = biasLds[32 + uu];
            #pragma unroll
            for (int w = 0; w < 4; ++w) {
                pi += pf2[((w * 3 + 0) * 64 + plane) * 4 + reg];
                pF += pf2[((w * 3 + 1) * 64 + plane) * 4 + reg];
                pc += pf2[((w * 3 + 2) * 64 + plane) * 4 + reg];
            }
            float iv  = fast_sigmoid(pi);
            float fv  = fast_sigmoid(pF);
            float cin = fast_tanh(pc);
            float cn  = fv * cTile[tid] + iv * cin;
            cTile[tid] = cn;
            hn = fast_tanh(cn);
            unsigned int hbb = f2bf_bits(hn);
            unsigned int lbb = f2bf_bits(hn - bfbits2f(hbb));
            unsigned int* hb32 = (unsigned int*)g_hbuf;
            size_t di = (size_t)(t & 1) * (Bv * Uv)
                      + ((size_t)((u0 + uu) >> 1) * Bv + (r0 + r)) * 2 + (uu & 1);
            __hip_atomic_store(hb32 + di, (hbb << 16) | lbb, __ATOMIC_RELAXED,
                               __HIP_MEMORY_SCOPE_AGENT);
        }

        // ---- 7. drain (h store at coherence point), publish flag ----
        __asm__ volatile("s_waitcnt vmcnt(0)" ::: "memory");
        __syncthreads();   // (B) all stores drained; also guards partLds reuse
        if (tid == 0)
            __hip_atomic_store(&g_flag[(size_t)(g * WPG + c) * FPAD],
                               base + (unsigned)t + 1u,
                               __ATOMIC_RELAXED, __HIP_MEMORY_SCOPE_AGENT);

        // ---- 8. tail (off inter-WG critical path): out store, x(t+1) issue ----
        out[((size_t)(r0 + r) * Tv + t) * Uv + u0 + uu] = hn;

        if (pfch) {
            #pragma unroll
            for (int i = 0; i < 2; ++i) {
                int kt = kh * 2 + i;
                const float* p = x + ((size_t)(r0 + m) * Tv + (t + 1)) * Dv + kt * 32 + q * 8;
                xf[i * 2]     = *(const f32x4*)p;
                xf[i * 2 + 1] = *(const f32x4*)(p + 4);
            }
        }
        // no tail barrier: (B) already orders epilogue partLds reads vs next writes
    }
}

extern "C" void kernel_launch(void* const* d_in, const int* in_sizes, int n_in,
                              void* d_out, int out_size, void* d_ws, size_t ws_size,
                              hipStream_t stream) {
    (void)in_sizes; (void)n_in; (void)out_size; (void)d_ws; (void)ws_size;
    noglstm_kernel<<<dim3(128), dim3(256), 0, stream>>>(
        (const float*)d_in[0],
        (const float*)d_in[1], (const float*)d_in[2], (const float*)d_in[3],
        (const float*)d_in[4], (const float*)d_in[5], (const float*)d_in[6],
        (const float*)d_in[7], (const float*)d_in[8], (const float*)d_in[9],
        (const float*)d_in[10], (const float*)d_in[11],
        (float*)d_out);
}